// Round 2
// baseline (767.059 us; speedup 1.0000x reference)
//
#include <hip/hip_runtime.h>

#ifndef __has_builtin
#define __has_builtin(x) 0
#endif

// Problem constants (fixed by the reference):
constexpr int TN   = 1000;  // T
constexpr int BN   = 4096;  // B
constexpr int HID  = 32;    // hidden dim
constexpr int HH   = 15;    // func-net inner dim (padded to 16 in registers)
constexpr int OUTD = 8;     // output dim

__device__ __forceinline__ float fexp2(float x) {
#if __has_builtin(__builtin_amdgcn_exp2f)
  return __builtin_amdgcn_exp2f(x);
#else
  return exp2f(x);
#endif
}
__device__ __forceinline__ float frcp(float x) {
#if __has_builtin(__builtin_amdgcn_rcpf)
  return __builtin_amdgcn_rcpf(x);
#else
  return 1.0f / x;
#endif
}
// tanh(x) = 1 - 2/(exp2(x*2*log2e)+1); v_exp/v_rcp ~1ulp, saturates to +-1.
__device__ __forceinline__ float ftanh(float x) {
  float t = fexp2(x * 2.8853900817779268f);
  return fmaf(-2.0f, frcp(t + 1.0f), 1.0f);
}

// row_ror:K within the 16-lane DPP row; K must be a compile-time constant.
template <int K>
__device__ __forceinline__ float rotk(float x) {
  if constexpr (K == 0) {
    return x;
  } else {
    return __int_as_float(
        __builtin_amdgcn_mov_dpp(__float_as_int(x), 0x120 + K, 0xF, 0xF, true));
  }
}

#define REP16(M) M(0) M(1) M(2) M(3) M(4) M(5) M(6) M(7) \
                 M(8) M(9) M(10) M(11) M(12) M(13) M(14) M(15)

// 16 lanes per batch row. 4096*16 = 65536 threads = 1024 waves = 1 wave/SIMD.
// ALL weights live in ~160 named scalar VGPRs (no arrays -> no scratch:
// R1's VGPR_Count=88 proved the array form was demoted to scratch by SROA
// running before unroll).
__global__ __launch_bounds__(256, 1) void node_kernel(
    const float* __restrict__ times, const float* __restrict__ initial,
    const float* __restrict__ Wi, const float* __restrict__ bi,
    const float* __restrict__ Wf0, const float* __restrict__ bf0,
    const float* __restrict__ Wf1, const float* __restrict__ bf1,
    const float* __restrict__ Wf2, const float* __restrict__ bf2,
    const float* __restrict__ Wf3, const float* __restrict__ bf3,
    const float* __restrict__ Wl, const float* __restrict__ bl,
    float* __restrict__ out) {
  const int tid = blockIdx.x * 256 + threadIdx.x;
  const int row = tid >> 4;   // batch row, 0..4095
  const int q   = tid & 15;   // position within the 16-lane ring

  // DPP direction probe: makes the ring indexing below correct under either
  // hardware rotate convention.
  int s1 = __builtin_amdgcn_mov_dpp(q, 0x121, 0xF, 0xF, true);
  const int dir = (s1 == ((q + 1) & 15)) ? 1 : -1;

  const bool qv = (q < HH);
  float b0v = qv ? bf0[q] : 0.f;
  float b1v = qv ? bf1[q] : 0.f;
  float b2v = qv ? bf2[q] : 0.f;
  float b30 = bf3[2 * q + 0];
  float b31 = bf3[2 * q + 1];
  float blv = bl[q & 7];

  // --- named-scalar weight registers, pre-rotated into ring order ---
#define DECLW(k) float w0a_##k, w0b_##k, w1_##k, w2_##k, w3a_##k, w3b_##k, \
                        wla_##k, wlb_##k;
  REP16(DECLW)
#undef DECLW

#define INITW(k)                                                     \
  {                                                                  \
    int p = (q + dir * (k)) & 15;                                    \
    bool pv = (p < HH);                                              \
    w0a_##k = qv ? Wf0[(2 * p + 0) * HH + q] : 0.f;                  \
    w0b_##k = qv ? Wf0[(2 * p + 1) * HH + q] : 0.f;                  \
    w1_##k  = (pv && qv) ? Wf1[p * HH + q] : 0.f;                    \
    w2_##k  = (pv && qv) ? Wf2[p * HH + q] : 0.f;                    \
    w3a_##k = pv ? Wf3[p * HID + 2 * q + 0] : 0.f;                   \
    w3b_##k = pv ? Wf3[p * HID + 2 * q + 1] : 0.f;                   \
    wla_##k = Wl[(2 * p + 0) * OUTD + (q & 7)];                      \
    wlb_##k = Wl[(2 * p + 1) * OUTD + (q & 7)];                      \
  }
  REP16(INITW)
#undef INITW

  // --- h0 = initial @ Wi + bi ; this lane owns components 2q, 2q+1
  float h0 = bi[2 * q + 0];
  float h1 = bi[2 * q + 1];
  {
    const float* ini = initial + (size_t)row * 16;
#pragma unroll
    for (int i = 0; i < 16; ++i) {
      float x = ini[i];
      h0 = fmaf(x, Wi[i * HID + 2 * q + 0], h0);
      h1 = fmaf(x, Wi[i * HID + 2 * q + 1], h1);
    }
  }

  float* op = out + (size_t)row * (TN * OUTD) + (q & 7);
  const bool do_store = (q < OUTD);

#pragma unroll 1
  for (int t = 0; t < TN; ++t) {
    float dtv = 0.0f;
    if (t + 1 < TN) dtv = times[t + 1] - times[t];

    // --- layer0 (z0) + fused output projection, sharing h rotations.
    // Independent accumulator per (input-component, purpose): 4 chains, each
    // touched once per k -> dependent-FMA reuse distance >= 6 instrs.
    float za = b0v, zb = 0.f, oa = blv, ob = 0.f;
#define LP0(k)                                           \
  {                                                      \
    float hk0 = rotk<k>(h0), hk1 = rotk<k>(h1);          \
    za = fmaf(hk0, w0a_##k, za);                         \
    zb = fmaf(hk1, w0b_##k, zb);                         \
    oa = fmaf(hk0, wla_##k, oa);                         \
    ob = fmaf(hk1, wlb_##k, ob);                         \
  }
    REP16(LP0)
#undef LP0
    float z0 = ftanh(za + zb);
    if (do_store) op[t * OUTD] = oa + ob;

    // --- layer1 (4 chains)
    float a10 = b1v, a11 = 0.f, a12 = 0.f, a13 = 0.f;
#define LP1(k)                                                        \
  {                                                                   \
    float zk = rotk<k>(z0);                                           \
    if constexpr (((k) & 3) == 0) a10 = fmaf(zk, w1_##k, a10);        \
    else if constexpr (((k) & 3) == 1) a11 = fmaf(zk, w1_##k, a11);   \
    else if constexpr (((k) & 3) == 2) a12 = fmaf(zk, w1_##k, a12);   \
    else a13 = fmaf(zk, w1_##k, a13);                                 \
  }
    REP16(LP1)
#undef LP1
    float z1 = ftanh((a10 + a11) + (a12 + a13));

    // --- layer2 (4 chains)
    float a20 = b2v, a21 = 0.f, a22 = 0.f, a23 = 0.f;
#define LP2(k)                                                        \
  {                                                                   \
    float zk = rotk<k>(z1);                                           \
    if constexpr (((k) & 3) == 0) a20 = fmaf(zk, w2_##k, a20);        \
    else if constexpr (((k) & 3) == 1) a21 = fmaf(zk, w2_##k, a21);   \
    else if constexpr (((k) & 3) == 2) a22 = fmaf(zk, w2_##k, a22);   \
    else a23 = fmaf(zk, w2_##k, a23);                                 \
  }
    REP16(LP2)
#undef LP2
    float z2 = ftanh((a20 + a21) + (a22 + a23));

    // --- layer3 (back to 32-dim), 4 chains, + Euler update
    float y0a = b30, y0b = 0.f, y1a = b31, y1b = 0.f;
#define LP3(k)                                           \
  {                                                      \
    float zk = rotk<k>(z2);                              \
    if constexpr (((k) & 1) == 0) {                      \
      y0a = fmaf(zk, w3a_##k, y0a);                      \
      y1a = fmaf(zk, w3b_##k, y1a);                      \
    } else {                                             \
      y0b = fmaf(zk, w3a_##k, y0b);                      \
      y1b = fmaf(zk, w3b_##k, y1b);                      \
    }                                                    \
  }
    REP16(LP3)
#undef LP3
    h0 = fmaf(dtv, y0a + y0b, h0);
    h1 = fmaf(dtv, y1a + y1b, h1);
  }
}

extern "C" void kernel_launch(void* const* d_in, const int* in_sizes, int n_in,
                              void* d_out, int out_size, void* d_ws, size_t ws_size,
                              hipStream_t stream) {
  (void)in_sizes; (void)n_in; (void)d_ws; (void)ws_size; (void)out_size;
  const float* times   = (const float*)d_in[0];
  const float* initial = (const float*)d_in[1];
  const float* Wi  = (const float*)d_in[2];
  const float* bi  = (const float*)d_in[3];
  const float* Wf0 = (const float*)d_in[4];
  const float* bf0 = (const float*)d_in[5];
  const float* Wf1 = (const float*)d_in[6];
  const float* bf1 = (const float*)d_in[7];
  const float* Wf2 = (const float*)d_in[8];
  const float* bf2 = (const float*)d_in[9];
  const float* Wf3 = (const float*)d_in[10];
  const float* bf3 = (const float*)d_in[11];
  const float* Wl  = (const float*)d_in[12];
  const float* bl  = (const float*)d_in[13];

  dim3 grid((BN * 16) / 256);  // 256 blocks -> 1 block/CU, 1 wave/SIMD
  dim3 block(256);
  hipLaunchKernelGGL(node_kernel, grid, block, 0, stream,
                     times, initial, Wi, bi, Wf0, bf0, Wf1, bf1,
                     Wf2, bf2, Wf3, bf3, Wl, bl, (float*)d_out);
}

// Round 3
// 703.532 us; speedup vs baseline: 1.0903x; 1.0903x over previous
//
#include <hip/hip_runtime.h>

#ifndef __has_builtin
#define __has_builtin(x) 0
#endif

// Problem constants (fixed by the reference):
constexpr int TN   = 1000;  // T
constexpr int BN   = 4096;  // B
constexpr int HID  = 32;    // hidden dim
constexpr int HH   = 15;    // func-net inner dim (padded to 16 in registers)
constexpr int OUTD = 8;     // output dim

__device__ __forceinline__ float fexp2(float x) {
#if __has_builtin(__builtin_amdgcn_exp2f)
  return __builtin_amdgcn_exp2f(x);
#else
  return exp2f(x);
#endif
}
__device__ __forceinline__ float frcp(float x) {
#if __has_builtin(__builtin_amdgcn_rcpf)
  return __builtin_amdgcn_rcpf(x);
#else
  return 1.0f / x;
#endif
}
// tanh(x) = 1 - 2/(exp2(x*2*log2e)+1); v_exp/v_rcp ~1ulp, saturates to +-1.
__device__ __forceinline__ float ftanh(float x) {
  float t = fexp2(x * 2.8853900817779268f);
  return fmaf(-2.0f, frcp(t + 1.0f), 1.0f);
}

// row_ror:K within the 16-lane DPP row; K must be a compile-time constant.
template <int K>
__device__ __forceinline__ float rotk(float x) {
  if constexpr (K == 0) {
    return x;
  } else {
    return __int_as_float(
        __builtin_amdgcn_mov_dpp(__float_as_int(x), 0x120 + K, 0xF, 0xF, true));
  }
}

// Pin a value into a real VGPR. The result of an inline asm cannot be
// rematerialized by the register allocator, so the value stays resident for
// its whole live range instead of being re-loaded from memory inside the
// t-loop (R1/R2: VGPR_Count=88 proved the 128 weight loads were being
// re-executed/AGPR-shuffled every iteration — the ~2.4x overhead).
#define PIN(x) asm volatile("" : "+v"(x))

#define REP16(M) M(0) M(1) M(2) M(3) M(4) M(5) M(6) M(7) \
                 M(8) M(9) M(10) M(11) M(12) M(13) M(14) M(15)

// 16 lanes per batch row. 4096*16 = 65536 threads = 1024 waves = 1 wave/SIMD.
__global__ __launch_bounds__(256, 1) void node_kernel(
    const float* __restrict__ times, const float* __restrict__ initial,
    const float* __restrict__ Wi, const float* __restrict__ bi,
    const float* __restrict__ Wf0, const float* __restrict__ bf0,
    const float* __restrict__ Wf1, const float* __restrict__ bf1,
    const float* __restrict__ Wf2, const float* __restrict__ bf2,
    const float* __restrict__ Wf3, const float* __restrict__ bf3,
    const float* __restrict__ Wl, const float* __restrict__ bl,
    float* __restrict__ out) {
  const int tid = blockIdx.x * 256 + threadIdx.x;
  const int row = tid >> 4;   // batch row, 0..4095
  const int q   = tid & 15;   // position within the 16-lane ring

  // DPP direction probe: makes the ring indexing below correct under either
  // hardware rotate convention.
  int s1 = __builtin_amdgcn_mov_dpp(q, 0x121, 0xF, 0xF, true);
  const int dir = (s1 == ((q + 1) & 15)) ? 1 : -1;

  const bool qv = (q < HH);
  float b0v = qv ? bf0[q] : 0.f;
  float b1v = qv ? bf1[q] : 0.f;
  float b2v = qv ? bf2[q] : 0.f;
  float b30 = bf3[2 * q + 0];
  float b31 = bf3[2 * q + 1];
  float blv = bl[q & 7];
  PIN(b0v); PIN(b1v); PIN(b2v); PIN(b30); PIN(b31); PIN(blv);

  // --- named-scalar weight registers, pre-rotated into ring order ---
#define DECLW(k) float w0a_##k, w0b_##k, w1_##k, w2_##k, w3a_##k, w3b_##k, \
                        wla_##k, wlb_##k;
  REP16(DECLW)
#undef DECLW

#define INITW(k)                                                     \
  {                                                                  \
    int p = (q + dir * (k)) & 15;                                    \
    bool pv = (p < HH);                                              \
    w0a_##k = qv ? Wf0[(2 * p + 0) * HH + q] : 0.f;                  \
    w0b_##k = qv ? Wf0[(2 * p + 1) * HH + q] : 0.f;                  \
    w1_##k  = (pv && qv) ? Wf1[p * HH + q] : 0.f;                    \
    w2_##k  = (pv && qv) ? Wf2[p * HH + q] : 0.f;                    \
    w3a_##k = pv ? Wf3[p * HID + 2 * q + 0] : 0.f;                   \
    w3b_##k = pv ? Wf3[p * HID + 2 * q + 1] : 0.f;                   \
    wla_##k = Wl[(2 * p + 0) * OUTD + (q & 7)];                      \
    wlb_##k = Wl[(2 * p + 1) * OUTD + (q & 7)];                      \
    PIN(w0a_##k); PIN(w0b_##k); PIN(w1_##k); PIN(w2_##k);            \
    PIN(w3a_##k); PIN(w3b_##k); PIN(wla_##k); PIN(wlb_##k);          \
  }
  REP16(INITW)
#undef INITW

  // --- h0 = initial @ Wi + bi ; this lane owns components 2q, 2q+1
  float h0 = bi[2 * q + 0];
  float h1 = bi[2 * q + 1];
  {
    const float* ini = initial + (size_t)row * 16;
#pragma unroll
    for (int i = 0; i < 16; ++i) {
      float x = ini[i];
      h0 = fmaf(x, Wi[i * HID + 2 * q + 0], h0);
      h1 = fmaf(x, Wi[i * HID + 2 * q + 1], h1);
    }
  }

  float* op = out + (size_t)row * (TN * OUTD) + (q & 7);
  const bool do_store = (q < OUTD);

#pragma unroll 1
  for (int t = 0; t < TN; ++t) {
    float dtv = 0.0f;
    if (t + 1 < TN) dtv = times[t + 1] - times[t];

    // --- layer0 (z0) + fused output projection, sharing h rotations.
    // 4 independent accumulator chains; consecutive same-chain FMAs are >=6
    // instructions apart -> 4-cyc FMA latency fully covered.
    float za = b0v, zb = 0.f, oa = blv, ob = 0.f;
#define LP0(k)                                           \
  {                                                      \
    float hk0 = rotk<k>(h0), hk1 = rotk<k>(h1);          \
    za = fmaf(hk0, w0a_##k, za);                         \
    zb = fmaf(hk1, w0b_##k, zb);                         \
    oa = fmaf(hk0, wla_##k, oa);                         \
    ob = fmaf(hk1, wlb_##k, ob);                         \
  }
    REP16(LP0)
#undef LP0
    float z0 = ftanh(za + zb);
    if (do_store) op[t * OUTD] = oa + ob;

    // --- layer1 (4 chains)
    float a10 = b1v, a11 = 0.f, a12 = 0.f, a13 = 0.f;
#define LP1(k)                                                        \
  {                                                                   \
    float zk = rotk<k>(z0);                                           \
    if constexpr (((k) & 3) == 0) a10 = fmaf(zk, w1_##k, a10);        \
    else if constexpr (((k) & 3) == 1) a11 = fmaf(zk, w1_##k, a11);   \
    else if constexpr (((k) & 3) == 2) a12 = fmaf(zk, w1_##k, a12);   \
    else a13 = fmaf(zk, w1_##k, a13);                                 \
  }
    REP16(LP1)
#undef LP1
    float z1 = ftanh((a10 + a11) + (a12 + a13));

    // --- layer2 (4 chains)
    float a20 = b2v, a21 = 0.f, a22 = 0.f, a23 = 0.f;
#define LP2(k)                                                        \
  {                                                                   \
    float zk = rotk<k>(z1);                                           \
    if constexpr (((k) & 3) == 0) a20 = fmaf(zk, w2_##k, a20);        \
    else if constexpr (((k) & 3) == 1) a21 = fmaf(zk, w2_##k, a21);   \
    else if constexpr (((k) & 3) == 2) a22 = fmaf(zk, w2_##k, a22);   \
    else a23 = fmaf(zk, w2_##k, a23);                                 \
  }
    REP16(LP2)
#undef LP2
    float z2 = ftanh((a20 + a21) + (a22 + a23));

    // --- layer3 (back to 32-dim), 4 chains, + Euler update
    float y0a = b30, y0b = 0.f, y1a = b31, y1b = 0.f;
#define LP3(k)                                           \
  {                                                      \
    float zk = rotk<k>(z2);                              \
    if constexpr (((k) & 1) == 0) {                      \
      y0a = fmaf(zk, w3a_##k, y0a);                      \
      y1a = fmaf(zk, w3b_##k, y1a);                      \
    } else {                                             \
      y0b = fmaf(zk, w3a_##k, y0b);                      \
      y1b = fmaf(zk, w3b_##k, y1b);                      \
    }                                                    \
  }
    REP16(LP3)
#undef LP3
    h0 = fmaf(dtv, y0a + y0b, h0);
    h1 = fmaf(dtv, y1a + y1b, h1);
  }
}

extern "C" void kernel_launch(void* const* d_in, const int* in_sizes, int n_in,
                              void* d_out, int out_size, void* d_ws, size_t ws_size,
                              hipStream_t stream) {
  (void)in_sizes; (void)n_in; (void)d_ws; (void)ws_size; (void)out_size;
  const float* times   = (const float*)d_in[0];
  const float* initial = (const float*)d_in[1];
  const float* Wi  = (const float*)d_in[2];
  const float* bi  = (const float*)d_in[3];
  const float* Wf0 = (const float*)d_in[4];
  const float* bf0 = (const float*)d_in[5];
  const float* Wf1 = (const float*)d_in[6];
  const float* bf1 = (const float*)d_in[7];
  const float* Wf2 = (const float*)d_in[8];
  const float* bf2 = (const float*)d_in[9];
  const float* Wf3 = (const float*)d_in[10];
  const float* bf3 = (const float*)d_in[11];
  const float* Wl  = (const float*)d_in[12];
  const float* bl  = (const float*)d_in[13];

  dim3 grid((BN * 16) / 256);  // 256 blocks -> 1 block/CU, 1 wave/SIMD
  dim3 block(256);
  hipLaunchKernelGGL(node_kernel, grid, block, 0, stream,
                     times, initial, Wi, bi, Wf0, bf0, Wf1, bf1,
                     Wf2, bf2, Wf3, bf3, Wl, bl, (float*)d_out);
}

// Round 4
// 653.454 us; speedup vs baseline: 1.1739x; 1.0766x over previous
//
#include <hip/hip_runtime.h>

#ifndef __has_builtin
#define __has_builtin(x) 0
#endif

// Problem constants (fixed by the reference):
constexpr int TN   = 1000;  // T
constexpr int BN   = 4096;  // B
constexpr int HID  = 32;    // hidden dim
constexpr int HH   = 15;    // func-net inner dim (padded to 16 in registers)
constexpr int OUTD = 8;     // output dim

typedef float v2f __attribute__((ext_vector_type(2)));

__device__ __forceinline__ float fexp2(float x) {
#if __has_builtin(__builtin_amdgcn_exp2f)
  return __builtin_amdgcn_exp2f(x);
#else
  return exp2f(x);
#endif
}
__device__ __forceinline__ float frcp(float x) {
#if __has_builtin(__builtin_amdgcn_rcpf)
  return __builtin_amdgcn_rcpf(x);
#else
  return 1.0f / x;
#endif
}
// tanh(x) = 1 - 2/(exp2(x*2*log2e)+1); v_exp/v_rcp ~1ulp, saturates to +-1.
__device__ __forceinline__ float ftanh(float x) {
  float t = fexp2(x * 2.8853900817779268f);
  return fmaf(-2.0f, frcp(t + 1.0f), 1.0f);
}

// row_ror:K within the 16-lane DPP row; K must be a compile-time constant.
template <int K>
__device__ __forceinline__ float rotk(float x) {
  if constexpr (K == 0) {
    return x;
  } else {
    return __int_as_float(
        __builtin_amdgcn_mov_dpp(__float_as_int(x), 0x120 + K, 0xF, 0xF, true));
  }
}

// v_pk_fma_f32: d = a*b + c elementwise on float2 (full-rate packed fp32).
__device__ __forceinline__ v2f pkfma(v2f a, v2f b, v2f c) {
  return __builtin_elementwise_fma(a, b, c);
}

#define PIN(x) asm volatile("" : "+v"(x))

#define REP16(M) M(0) M(1) M(2) M(3) M(4) M(5) M(6) M(7) \
                 M(8) M(9) M(10) M(11) M(12) M(13) M(14) M(15)
#define REP8(M) M(0) M(1) M(2) M(3) M(4) M(5) M(6) M(7)

// 16 lanes per batch row. 4096*16 = 65536 threads = 1024 waves = 1 wave/SIMD.
__global__ __launch_bounds__(256, 1) void node_kernel(
    const float* __restrict__ times, const float* __restrict__ initial,
    const float* __restrict__ Wi, const float* __restrict__ bi,
    const float* __restrict__ Wf0, const float* __restrict__ bf0,
    const float* __restrict__ Wf1, const float* __restrict__ bf1,
    const float* __restrict__ Wf2, const float* __restrict__ bf2,
    const float* __restrict__ Wf3, const float* __restrict__ bf3,
    const float* __restrict__ Wl, const float* __restrict__ bl,
    float* __restrict__ out) {
  const int tid = blockIdx.x * 256 + threadIdx.x;
  const int row = tid >> 4;   // batch row, 0..4095
  const int q   = tid & 15;   // position within the 16-lane ring

  // DPP direction probe: correct under either hardware rotate convention.
  int s1 = __builtin_amdgcn_mov_dpp(q, 0x121, 0xF, 0xF, true);
  const int dir = (s1 == ((q + 1) & 15)) ? 1 : -1;

  const bool qv = (q < HH);
  float b0v = qv ? bf0[q] : 0.f;
  float b1v = qv ? bf1[q] : 0.f;
  float b2v = qv ? bf2[q] : 0.f;
  float b30 = bf3[2 * q + 0];
  float b31 = bf3[2 * q + 1];
  float blv = bl[q & 7];
  PIN(b0v); PIN(b1v); PIN(b2v); PIN(b30); PIN(b31); PIN(blv);

  // --- weight registers as float2 pairs, pre-rotated into ring order ---
  // wp0_k = (Wf0[2p][q], Wf0[2p+1][q])   pairs with rotated (h0,h1)
  // wlp_k = (Wl[2p][q&7], Wl[2p+1][q&7]) same pairing (shares rotations)
  // wp3_k = (Wf3[p][2q], Wf3[p][2q+1])   splat-z times component pair
  // wp1_j / wp2_j = (w[p(2j)][q], w[p(2j+1)][q]) pairs consecutive rotations
#define DECLK(k) v2f wp0_##k, wlp_##k, wp3_##k;
  REP16(DECLK)
#undef DECLK
#define DECLJ(j) v2f wp1_##j, wp2_##j;
  REP8(DECLJ)
#undef DECLJ

#define INITK(k)                                                        \
  {                                                                     \
    int p = (q + dir * (k)) & 15;                                       \
    bool pv = (p < HH);                                                 \
    wp0_##k = (v2f){qv ? Wf0[(2 * p + 0) * HH + q] : 0.f,               \
                    qv ? Wf0[(2 * p + 1) * HH + q] : 0.f};              \
    wlp_##k = (v2f){Wl[(2 * p + 0) * OUTD + (q & 7)],                   \
                    Wl[(2 * p + 1) * OUTD + (q & 7)]};                  \
    wp3_##k = (v2f){pv ? Wf3[p * HID + 2 * q + 0] : 0.f,                \
                    pv ? Wf3[p * HID + 2 * q + 1] : 0.f};               \
    PIN(wp0_##k); PIN(wlp_##k); PIN(wp3_##k);                           \
  }
  REP16(INITK)
#undef INITK

#define INITJ(j)                                                        \
  {                                                                     \
    int p0 = (q + dir * (2 * (j) + 0)) & 15;                            \
    int p1 = (q + dir * (2 * (j) + 1)) & 15;                            \
    wp1_##j = (v2f){(p0 < HH && qv) ? Wf1[p0 * HH + q] : 0.f,           \
                    (p1 < HH && qv) ? Wf1[p1 * HH + q] : 0.f};          \
    wp2_##j = (v2f){(p0 < HH && qv) ? Wf2[p0 * HH + q] : 0.f,           \
                    (p1 < HH && qv) ? Wf2[p1 * HH + q] : 0.f};          \
    PIN(wp1_##j); PIN(wp2_##j);                                         \
  }
  REP8(INITJ)
#undef INITJ

  // --- h0 = initial @ Wi + bi ; this lane owns components 2q, 2q+1
  float h0 = bi[2 * q + 0];
  float h1 = bi[2 * q + 1];
  {
    const float* ini = initial + (size_t)row * 16;
#pragma unroll
    for (int i = 0; i < 16; ++i) {
      float x = ini[i];
      h0 = fmaf(x, Wi[i * HID + 2 * q + 0], h0);
      h1 = fmaf(x, Wi[i * HID + 2 * q + 1], h1);
    }
  }

  float* op = out + (size_t)row * (TN * OUTD) + (q & 7);
  const bool do_store = (q < OUTD);
  float tprev = times[0];

#pragma unroll 1
  for (int t = 0; t < TN; ++t) {
    // one SMEM load per step, issued at the top, consumed at the bottom
    float tcur = times[(t + 1 < TN) ? (t + 1) : (TN - 1)];
    float dtv = tcur - tprev;   // == 0 at t == TN-1 by construction
    tprev = tcur;

    // --- layer0 (z0) + fused output projection, sharing h rotations.
    // Packed accumulators: 2 chains each, alternating k (dep distance >= 8).
    v2f zA = {b0v, 0.f}, zB = {0.f, 0.f};
    v2f oA = {blv, 0.f}, oB = {0.f, 0.f};
#define LP0(k)                                                 \
  {                                                            \
    float hk0 = rotk<k>(h0);                                   \
    float hk1 = rotk<k>(h1);                                   \
    v2f hk = {hk0, hk1};                                       \
    if constexpr (((k) & 1) == 0) {                            \
      zA = pkfma(hk, wp0_##k, zA);                             \
      oA = pkfma(hk, wlp_##k, oA);                             \
    } else {                                                   \
      zB = pkfma(hk, wp0_##k, zB);                             \
      oB = pkfma(hk, wlp_##k, oB);                             \
    }                                                          \
  }
    REP16(LP0)
#undef LP0
    float z0 = ftanh((zA.x + zA.y) + (zB.x + zB.y));
    if (do_store) *op = (oA.x + oA.y) + (oB.x + oB.y);
    op += OUTD;

    // --- layer1: pair consecutive rotations (2j, 2j+1), 2 packed chains
    v2f a1A = {b1v, 0.f}, a1B = {0.f, 0.f};
#define LP1(j)                                                 \
  {                                                            \
    float e0 = rotk<2 * (j) + 0>(z0);                          \
    float e1 = rotk<2 * (j) + 1>(z0);                          \
    v2f e = {e0, e1};                                          \
    if constexpr (((j) & 1) == 0) a1A = pkfma(e, wp1_##j, a1A);\
    else                          a1B = pkfma(e, wp1_##j, a1B);\
  }
    REP8(LP1)
#undef LP1
    float z1 = ftanh((a1A.x + a1A.y) + (a1B.x + a1B.y));

    // --- layer2
    v2f a2A = {b2v, 0.f}, a2B = {0.f, 0.f};
#define LP2(j)                                                 \
  {                                                            \
    float e0 = rotk<2 * (j) + 0>(z1);                          \
    float e1 = rotk<2 * (j) + 1>(z1);                          \
    v2f e = {e0, e1};                                          \
    if constexpr (((j) & 1) == 0) a2A = pkfma(e, wp2_##j, a2A);\
    else                          a2B = pkfma(e, wp2_##j, a2B);\
  }
    REP8(LP2)
#undef LP2
    float z2 = ftanh((a2A.x + a2A.y) + (a2B.x + a2B.y));

    // --- layer3: splat z * (w3a, w3b) pair into packed (y0, y1) accumulators
    v2f yA = {b30, b31}, yB = {0.f, 0.f};
#define LP3(k)                                                 \
  {                                                            \
    float zk = rotk<k>(z2);                                    \
    v2f zz = {zk, zk};                                         \
    if constexpr (((k) & 1) == 0) yA = pkfma(zz, wp3_##k, yA); \
    else                          yB = pkfma(zz, wp3_##k, yB); \
  }
    REP16(LP3)
#undef LP3
    h0 = fmaf(dtv, yA.x + yB.x, h0);
    h1 = fmaf(dtv, yA.y + yB.y, h1);
  }
}

extern "C" void kernel_launch(void* const* d_in, const int* in_sizes, int n_in,
                              void* d_out, int out_size, void* d_ws, size_t ws_size,
                              hipStream_t stream) {
  (void)in_sizes; (void)n_in; (void)d_ws; (void)ws_size; (void)out_size;
  const float* times   = (const float*)d_in[0];
  const float* initial = (const float*)d_in[1];
  const float* Wi  = (const float*)d_in[2];
  const float* bi  = (const float*)d_in[3];
  const float* Wf0 = (const float*)d_in[4];
  const float* bf0 = (const float*)d_in[5];
  const float* Wf1 = (const float*)d_in[6];
  const float* bf1 = (const float*)d_in[7];
  const float* Wf2 = (const float*)d_in[8];
  const float* bf2 = (const float*)d_in[9];
  const float* Wf3 = (const float*)d_in[10];
  const float* bf3 = (const float*)d_in[11];
  const float* Wl  = (const float*)d_in[12];
  const float* bl  = (const float*)d_in[13];

  dim3 grid((BN * 16) / 256);  // 256 blocks -> 1 block/CU, 1 wave/SIMD
  dim3 block(256);
  hipLaunchKernelGGL(node_kernel, grid, block, 0, stream,
                     times, initial, Wi, bi, Wf0, bf0, Wf1, bf1,
                     Wf2, bf2, Wf3, bf3, Wl, bl, (float*)d_out);
}